// Round 1
// baseline (675.913 us; speedup 1.0000x reference)
//
#include <hip/hip_runtime.h>
#include <math.h>

// Preisach hysteresis, N=256, T variable (2000 in bench).
// Row-staircase formulation: per row i, state is +1 for j<=c_i, -1 for c_i<j<=i.
//   up-step   (h_cur > h_prev): rows with alpha_i < h_cur  -> c_i = i
//   down-step (h_cur < h_prev): all rows -> c_i = min(c_i, k), k = max{j : x_j <= h_cur}
// b[t] = sum_i (2*P_i(c_i) - Tot_i) / 32896 * scale + offset
// G-table G_i[c+1] = 2*P_i(c) - Tot_i precomputed in LDS per block.

#define NMESH 256
#define NB 4          // row-group blocks
#define CH 64         // time-chunk length
#define CBS 65        // chunk buffer stride (pad: conflict-free column reduce)

__global__ void init_out_kernel(const float* __restrict__ offset,
                                float* __restrict__ out, int T) {
    int t = blockIdx.x * blockDim.x + threadIdx.x;
    if (t < T) out[t] = offset[0];
}

__global__ __launch_bounds__(64)
void hyst_scan_kernel(const float* __restrict__ h,
                      const float* __restrict__ raw,
                      const float* __restrict__ scale,
                      float* __restrict__ out, int T) {
    // block b owns rows i = 4*lane + b  (64 rows, lengths balanced across blocks)
    // G slice size for block b: sum_l (4l + b + 2) = 8192 + 64*b  <= 8384 floats
    __shared__ float G[8448];
    __shared__ float cb[CH * CBS];

    const int b = blockIdx.x;
    const int l = threadIdx.x;
    const int row = 4 * l + b;
    const float delta = 1.0f / 255.0f;   // matches fl(1/255) used by jnp.linspace

    // lane-local offset into G: sum_{m<l} (4m + b + 2) = 2l(l-1) + (b+2)l
    const int loff = 2 * l * (l - 1) + (b + 2) * l;

    // ---- build G row: softplus + prefix, then G[e] = 2*P - Tot, e = c+1 in [0, row+1]
    {
        const int tri = row * (row + 1) / 2;
        float run = 0.0f;
        G[loff] = 0.0f;                       // P(-1) = 0
        for (int j = 0; j <= row; ++j) {
            float r = raw[tri + j];
            // jax.nn.softplus(x) = max(x,0) + log1p(exp(-|x|))
            float sp = fmaxf(r, 0.0f) + log1pf(expf(-fabsf(r)));
            run += sp;
            G[loff + 1 + j] = run;
        }
        const float tot = run;
        for (int e = 0; e <= row + 1; ++e)
            G[loff + e] = 2.0f * G[loff + e] - tot;
    }
    __syncthreads();

    const float sc = scale[0];
    const float inv_tri = 1.0f / 32896.0f;   // N*(N+1)/2
    const float alpha_i = (float)row * delta;

    int c = -1;            // initial state: all -1  (c_i = -1)
    float h_prev = 0.0f;   // hs[0] = H_MIN

    int t = 0;
    while (t < T) {
        const int steps = min(CH, T - t);
        #pragma unroll 4
        for (int s = 0; s < steps; ++s) {
            const float h_cur = h[t + s];            // uniform -> scalar load
            if (h_cur > h_prev) {
                // where(yy >= h_cur, state, 1.0): flip rows with alpha < h_cur (strict)
                if (alpha_i < h_cur) c = row;
            } else if (h_cur < h_prev) {
                // where(xx <= h_cur, state, -1.0): k = max j with x_j <= h_cur
                int k = (int)(h_cur * 255.0f);
                if (k > 255) k = 255;
                while (k < 255 && (float)(k + 1) * delta <= h_cur) ++k;
                while (k > 0 && (float)k * delta > h_cur) --k;
                c = min(c, k);
            }
            h_prev = h_cur;
            cb[s * CBS + l] = G[loff + c + 1];       // gather off the serial chain
        }
        __syncthreads();
        // lane l reduces time-row l (stride-65 -> conflict-free)
        if (l < steps) {
            float sum = 0.0f;
            #pragma unroll 8
            for (int j = 0; j < 64; ++j) sum += cb[l * CBS + j];
            atomicAdd(&out[t + l], sum * inv_tri * sc);  // device-scope, 4 adders/addr
        }
        __syncthreads();
        t += steps;
    }
}

extern "C" void kernel_launch(void* const* d_in, const int* in_sizes, int n_in,
                              void* d_out, int out_size, void* d_ws, size_t ws_size,
                              hipStream_t stream) {
    const float* h      = (const float*)d_in[0];
    const float* raw    = (const float*)d_in[1];
    const float* offset = (const float*)d_in[2];
    const float* scale  = (const float*)d_in[3];
    float* out = (float*)d_out;
    const int T = in_sizes[0];

    init_out_kernel<<<(T + 255) / 256, 256, 0, stream>>>(offset, out, T);
    hyst_scan_kernel<<<NB, 64, 0, stream>>>(h, raw, scale, out, T);
}

// Round 2
// 279.389 us; speedup vs baseline: 2.4193x; 2.4193x over previous
//
#include <hip/hip_runtime.h>
#include <math.h>

// Preisach hysteresis, N=256. Row-staircase: per row i, state = +1 for j<=c_i,
// -1 for c_i<j<=i.  b[t] = sum_i G_i[c_i(t)+1] / 32896 * scale + offset,
// G_i[e] = 2*P_i(e-1) - Tot_i (P = row prefix sums of softplus(raw)).
//
// R2 restructure: step-uniform work (up/down direction, k/u thresholds) is
// precomputed per 64-step chunk into packed LDS codes (parallel, off the
// serial chain). The serial scan is then: broadcast-read 4 codes per
// ds_read_b128, branchless c-update (v_min + cndmask, ~8 cyc chain/step),
// LDS gather staged to a padded chunk buffer, block reduce + atomicAdd
// every 64 steps.

#define NB 4          // row-group blocks: block b owns rows 4*lane + b
#define CH 64         // time-chunk length
#define CBS 65        // chunk buffer stride: (s*65+l)%32 = (s+l)%32 -> 2-way, free

__global__ void init_out_kernel(const float* __restrict__ offset,
                                float* __restrict__ out, int T) {
    int t = blockIdx.x * blockDim.x + threadIdx.x;
    if (t < T) out[t] = offset[0];
}

__global__ __launch_bounds__(64)
void hyst_scan_kernel(const float* __restrict__ h,
                      const float* __restrict__ raw,
                      const float* __restrict__ scale,
                      float* __restrict__ out, int T) {
    // G slice for block b: sum_l (4l + b + 2) = 8192 + 64*b <= 8384 floats
    __shared__ float G[8448];
    __shared__ float cb[CH * CBS];
    __shared__ __align__(16) int codes[CH];

    const int b = blockIdx.x;
    const int l = threadIdx.x;
    const int row = 4 * l + b;
    const float delta = 1.0f / 255.0f;         // fl(1/255), matches jnp.linspace
    const int loff = 2 * l * (l - 1) + (b + 2) * l;

    // ---- G build: softplus + prefix, G[e] = 2*P - Tot, e = c+1 in [0,row+1]
    {
        const int tri = row * (row + 1) / 2;
        float run = 0.0f;
        G[loff] = 0.0f;                        // P(-1) = 0
        for (int j = 0; j <= row; ++j) {
            float r = raw[tri + j];
            // jax.nn.softplus(x) = max(x,0) + log1p(exp(-|x|))
            float sp = fmaxf(r, 0.0f) + log1pf(expf(-fabsf(r)));
            run += sp;
            G[loff + 1 + j] = run;
        }
        const float tot = run;
        for (int e = 0; e <= row + 1; ++e)
            G[loff + e] = 2.0f * G[loff + e] - tot;
    }

    const float sc = scale[0];
    const float inv_tri = 1.0f / 32896.0f;     // N*(N+1)/2
    const int gbase = loff + 1;

    int c = -1;                                // initial state: all -1

    for (int t0 = 0; t0 < T; t0 += CH) {
        const int steps = min(CH, T - t0);

        // ---- phase A (parallel): lane l packs code for step t0+l
        // code = (u << 16) | k ; update: c = min(c,k); if (row < u) c = row
        {
            int code = 256;                    // no-op: k=256, u=0
            const int t = t0 + l;
            if (l < steps) {
                const float hc = h[t];
                const float hp = (t == 0) ? 0.0f : h[t - 1];
                if (hc > hp) {
                    // u-1 = max{ i : (float)i*delta < hc }  (strict, as yy>=h keep)
                    int i = (int)(hc * 255.0f);
                    if (i > 255) i = 255;
                    while (i < 255 && (float)(i + 1) * delta < hc) ++i;
                    while (i >= 0 && (float)i * delta >= hc) --i;
                    code = ((i + 1) << 16) | 256;
                } else if (hc < hp) {
                    // k = max{ j : (float)j*delta <= hc }  (xx<=h keep)
                    int kk = (int)(hc * 255.0f);
                    if (kk > 255) kk = 255;
                    while (kk < 255 && (float)(kk + 1) * delta <= hc) ++kk;
                    while (kk > 0 && (float)kk * delta > hc) --kk;
                    code = kk;
                }
            }
            codes[l] = code;                   // pad lanes >= steps with no-op
        }
        __syncthreads();   // also covers G-build (1st iter) and cb reuse (later)

        // ---- phase B (serial chain): branchless scan, 4 codes per b128 read
        const int S4 = (steps + 3) & ~3;       // padded codes are no-ops
        #pragma unroll 2
        for (int s4 = 0; s4 < S4; s4 += 4) {
            const uint4 cd = *(const uint4*)&codes[s4];   // uniform -> broadcast
            {
                const int k = (int)(cd.x & 0xFFFFu), u = (int)(cd.x >> 16);
                c = min(c, k); if (row < u) c = row;
                cb[(s4 + 0) * CBS + l] = G[gbase + c];
            }
            {
                const int k = (int)(cd.y & 0xFFFFu), u = (int)(cd.y >> 16);
                c = min(c, k); if (row < u) c = row;
                cb[(s4 + 1) * CBS + l] = G[gbase + c];
            }
            {
                const int k = (int)(cd.z & 0xFFFFu), u = (int)(cd.z >> 16);
                c = min(c, k); if (row < u) c = row;
                cb[(s4 + 2) * CBS + l] = G[gbase + c];
            }
            {
                const int k = (int)(cd.w & 0xFFFFu), u = (int)(cd.w >> 16);
                c = min(c, k); if (row < u) c = row;
                cb[(s4 + 3) * CBS + l] = G[gbase + c];
            }
        }
        __syncthreads();

        // ---- phase C (parallel): lane l reduces time-row l (conflict-free)
        if (l < steps) {
            float sum = 0.0f;
            #pragma unroll 16
            for (int j = 0; j < 64; ++j) sum += cb[l * CBS + j];
            atomicAdd(&out[t0 + l], sum * inv_tri * sc);
        }
        __syncthreads();
    }
}

extern "C" void kernel_launch(void* const* d_in, const int* in_sizes, int n_in,
                              void* d_out, int out_size, void* d_ws, size_t ws_size,
                              hipStream_t stream) {
    const float* h      = (const float*)d_in[0];
    const float* raw    = (const float*)d_in[1];
    const float* offset = (const float*)d_in[2];
    const float* scale  = (const float*)d_in[3];
    float* out = (float*)d_out;
    const int T = in_sizes[0];

    init_out_kernel<<<(T + 255) / 256, 256, 0, stream>>>(offset, out, T);
    hyst_scan_kernel<<<NB, 64, 0, stream>>>(h, raw, scale, out, T);
}

// Round 3
// 269.028 us; speedup vs baseline: 2.5124x; 1.0385x over previous
//
#include <hip/hip_runtime.h>
#include <math.h>

// Preisach hysteresis, N=256. Row-staircase: per row i, state = +1 for j<=c_i,
// -1 for c_i<j<=i.  b[t] = sum_i G_i[c_i(t)+1] / 32896 * scale + offset,
// G_i[e] = 2*P_i(e-1) - Tot_i (P = row prefix sums of softplus(raw)).
//
// R3: (1) c-chain decoupled from gathers (16-step register batches; chain is
// c = max(min(c,k),r) ~ v_med3); (2) G stored column-major G2[e*64+l] so each
// lane gathers only bank l%32 (2-way = free) and only its own column (no
// barrier between build and gather); (3) all h loads + threshold searches
// hoisted into one upfront codes-fill phase (LDS, padded with no-ops).

#define NB 4            // row-group blocks: block b owns rows 4*lane + b
#define CH 64           // time-chunk length
#define CBS 65          // cb stride: (s*65+l)%32 = (s+l)%32 -> 2-way, free
#define CODES_CAP 2048  // codes superchunk (ints)
#define GE 258          // max G entries per lane (row+2 <= 257)

__global__ void init_out_kernel(const float* __restrict__ offset,
                                float* __restrict__ out, int T) {
    int t = blockIdx.x * blockDim.x + threadIdx.x;
    if (t < T) out[t] = offset[0];
}

__global__ __launch_bounds__(64)
void hyst_scan_kernel(const float* __restrict__ h,
                      const float* __restrict__ raw,
                      const float* __restrict__ scale,
                      float* __restrict__ out, int T) {
    __shared__ float G2[GE * 64];       // 66048 B, column-major: G2[e*64 + l]
    __shared__ float cb[CH * CBS];      // 16640 B
    __shared__ __align__(16) int codes[CODES_CAP];  // 8192 B

    const int b = blockIdx.x;
    const int l = threadIdx.x;
    const int row = 4 * l + b;
    const float delta = 1.0f / 255.0f;  // fl(1/255), matches jnp.linspace

    // ---- G build (lane-private column, bank l%32 only; no barrier needed)
    {
        const int tri = row * (row + 1) / 2;
        float run = 0.0f;
        G2[l] = 0.0f;                    // e = 0 -> P(-1) = 0
        for (int j = 0; j <= row; ++j) {
            float r = raw[tri + j];
            // jax.nn.softplus(x) = max(x,0) + log1p(exp(-|x|))
            float sp = fmaxf(r, 0.0f) + log1pf(expf(-fabsf(r)));
            run += sp;
            G2[(j + 1) * 64 + l] = run;
        }
        const float tot = run;
        for (int e = 0; e <= row + 1; ++e)
            G2[e * 64 + l] = 2.0f * G2[e * 64 + l] - tot;
    }

    const float sc = scale[0];
    const float inv_tri = 1.0f / 32896.0f;   // N*(N+1)/2

    int c = -1;                              // initial state: all -1

    for (int tb = 0; tb < T; tb += CODES_CAP) {
        // ---- phase 0: fill codes[0..CAP) for steps tb..tb+CAP (pad: no-op)
        // code = (u << 16) | k ; update: c = max(min(c, k), (row<u ? row : -1))
        for (int i = l; i < CODES_CAP; i += 64) {
            const int t = tb + i;
            int code = 256;                  // no-op: k=256, u=0
            if (t < T) {
                const float hc = h[t];
                const float hp = (t == 0) ? 0.0f : h[t - 1];
                if (hc > hp) {
                    // u-1 = max{ i : (float)i*delta < hc }  (yy >= h keeps)
                    int i2 = (int)(hc * 255.0f);
                    if (i2 > 255) i2 = 255;
                    while (i2 < 255 && (float)(i2 + 1) * delta < hc) ++i2;
                    while (i2 >= 0 && (float)i2 * delta >= hc) --i2;
                    code = ((i2 + 1) << 16) | 256;
                } else if (hc < hp) {
                    // k = max{ j : (float)j*delta <= hc }  (xx <= h keeps)
                    int kk = (int)(hc * 255.0f);
                    if (kk > 255) kk = 255;
                    while (kk < 255 && (float)(kk + 1) * delta <= hc) ++kk;
                    while (kk > 0 && (float)kk * delta > hc) --kk;
                    code = kk;
                }
            }
            codes[i] = code;
        }
        __syncthreads();

        const int tend = min(T, tb + CODES_CAP);
        for (int t0 = tb; t0 < tend; t0 += CH) {
            // ---- phase B: 4 sub-chunks of 16: chain first (registers), then
            //      16 independent gathers+stages (latency pipelined)
            const int cbase = t0 - tb;
            #pragma unroll
            for (int q = 0; q < 4; ++q) {
                const uint4 cd0 = *(const uint4*)&codes[cbase + q * 16 + 0];
                const uint4 cd1 = *(const uint4*)&codes[cbase + q * 16 + 4];
                const uint4 cd2 = *(const uint4*)&codes[cbase + q * 16 + 8];
                const uint4 cd3 = *(const uint4*)&codes[cbase + q * 16 + 12];
                const unsigned cw[16] = {cd0.x, cd0.y, cd0.z, cd0.w,
                                         cd1.x, cd1.y, cd1.z, cd1.w,
                                         cd2.x, cd2.y, cd2.z, cd2.w,
                                         cd3.x, cd3.y, cd3.z, cd3.w};
                int cs[16];
                #pragma unroll
                for (int s = 0; s < 16; ++s) {
                    const int k = (int)(cw[s] & 0xFFFFu);   // off-chain
                    const int u = (int)(cw[s] >> 16);       // off-chain
                    const int r = (row < u) ? row : -1;     // off-chain
                    c = max(min(c, k), r);                  // chain: ~med3
                    cs[s] = c;
                }
                #pragma unroll
                for (int s = 0; s < 16; ++s)
                    cb[(q * 16 + s) * CBS + l] = G2[(cs[s] + 1) * 64 + l];
            }
            __syncthreads();

            // ---- phase C: lane l reduces time-row l (conflict-free)
            const int steps = min(CH, T - t0);
            if (l < steps) {
                float sum = 0.0f;
                #pragma unroll
                for (int j = 0; j < 64; ++j) sum += cb[l * CBS + j];
                atomicAdd(&out[t0 + l], sum * inv_tri * sc);
            }
            __syncthreads();
        }
    }
}

extern "C" void kernel_launch(void* const* d_in, const int* in_sizes, int n_in,
                              void* d_out, int out_size, void* d_ws, size_t ws_size,
                              hipStream_t stream) {
    const float* h      = (const float*)d_in[0];
    const float* raw    = (const float*)d_in[1];
    const float* offset = (const float*)d_in[2];
    const float* scale  = (const float*)d_in[3];
    float* out = (float*)d_out;
    const int T = in_sizes[0];

    init_out_kernel<<<(T + 255) / 256, 256, 0, stream>>>(offset, out, T);
    hyst_scan_kernel<<<NB, 64, 0, stream>>>(h, raw, scale, out, T);
}

// Round 4
// 108.665 us; speedup vs baseline: 6.2201x; 2.4757x over previous
//
#include <hip/hip_runtime.h>
#include <math.h>

// Preisach hysteresis, N=256, parallel-in-time (clamp-scan) formulation.
//
// Per row i the state is a staircase: +1 for j<=c_i, -1 for c_i<j<=i.
// Step update: c = max(min(c, k_t), r_t) with
//   up   (h>hp): k=256, r = (row < u_t ? row : -1),  u_t = #{i : i*d < h}
//   down (h<hp): k = max{j : j*d <= h},  r = -1
// Clamps compose: chunk of steps == c -> max(min(c,HI),LO), (LO,HI) obtained
// by running the chunk on seeds (-1, 256).  3-pass scan:
//   K1: per-chunk codes + per-row (LO,HI) compose; G table build (global ws)
//   K2: serial combine over chunks -> entry state E[chunk][row]
//   K3: per-chunk replay (32 steps) + G gather/reduce -> out[t]   (no atomics)
//
// G layout ("pair packing"): lane l owns rows {l, 255-l, 64+l, 191-l};
// the concatenated column is exactly 518 floats for every lane.  Stored
// e-interleaved: addr = idx*64 + l  -> lane-private bank (2-way = free).
//   row l     : idx0 = 0        row 255-l : idx0 = l+2
//   row 64+l  : idx0 = 259      row 191-l : idx0 = 325+l
// G_r[e] = 2*P_r(e-1) - Tot_r,  P = prefix sums of softplus(raw), e in [0,r+1].

#define CL 32               // chunk length (time steps per chunk)
#define GSZ (518 * 64)      // packed G table, floats

__device__ __forceinline__ int make_code(const float* __restrict__ h, int t, int T) {
    const float delta = 1.0f / 255.0f;          // fl(1/255), matches jnp.linspace
    int code = 256;                              // no-op: k=256, u=0
    if (t < T) {
        const float hc = h[t];
        const float hp = (t == 0) ? 0.0f : h[t - 1];
        if (hc > hp) {
            // u-1 = max{ i : (float)i*delta < hc }   (yy >= h keeps state)
            int i2 = (int)(hc * 255.0f);
            if (i2 > 255) i2 = 255;
            while (i2 < 255 && (float)(i2 + 1) * delta < hc) ++i2;
            while (i2 >= 0 && (float)i2 * delta >= hc) --i2;
            code = ((i2 + 1) << 16) | 256;
        } else if (hc < hp) {
            // k = max{ j : (float)j*delta <= hc }    (xx <= h keeps state)
            int kk = (int)(hc * 255.0f);
            if (kk > 255) kk = 255;
            while (kk < 255 && (float)(kk + 1) * delta <= hc) ++kk;
            while (kk > 0 && (float)kk * delta > hc) --kk;
            code = kk;
        }
    }
    return code;
}

// ---- K1: blocks [0,NCH): codes + per-row clamp compose
//          blocks [NCH, NCH+256): G build for row (b - NCH)
__global__ __launch_bounds__(256)
void k1_compose_gbuild(const float* __restrict__ h, const float* __restrict__ raw,
                       int* __restrict__ codes, int2* __restrict__ lohi,
                       float* __restrict__ Gg, int T, int NCH) {
    const int b = blockIdx.x;
    if (b < NCH) {
        __shared__ int cds[CL];
        const int tid = threadIdx.x;
        if (tid < CL) {
            const int code = make_code(h, b * CL + tid, T);
            cds[tid] = code;
            codes[b * CL + tid] = code;
        }
        __syncthreads();
        const int r = tid;                       // thread = row
        int lo = -1, hi = 256;                   // identity clamp on [-1,255]
        #pragma unroll
        for (int s = 0; s < CL; ++s) {
            const int cd = cds[s];
            const int k = cd & 0xFFFF, u = cd >> 16;
            const int rr = (r < u) ? r : -1;
            lo = max(min(lo, k), rr);
            hi = max(min(hi, k), rr);
        }
        lohi[b * 256 + r] = make_int2(lo, hi);
    } else {
        // ---- G build, one wave per row
        if (threadIdx.x >= 64) return;
        const int r = b - NCH;
        const int l = threadIdx.x;
        const int tri = r * (r + 1) / 2;
        int lcol, idx0;
        if (r < 64)       { lcol = r;       idx0 = 0; }
        else if (r < 128) { lcol = r - 64;  idx0 = 259; }
        else if (r < 192) { lcol = 191 - r; idx0 = 325 + lcol; }
        else              { lcol = 255 - r; idx0 = lcol + 2; }

        float Pseg[4];
        float carry = 0.0f;
        const int nseg = r / 64 + 1;
        #pragma unroll
        for (int s = 0; s < 4; ++s) {
            Pseg[s] = 0.0f;
            if (s < nseg) {
                const int j = s * 64 + l;
                float v = 0.0f;
                if (j <= r) {
                    const float x = raw[tri + j];
                    // jax.nn.softplus(x) = max(x,0) + log1p(exp(-|x|))
                    v = fmaxf(x, 0.0f) + log1pf(expf(-fabsf(x)));
                }
                #pragma unroll
                for (int off = 1; off < 64; off <<= 1) {
                    const float w = __shfl_up(v, off);
                    if (l >= off) v += w;
                }
                Pseg[s] = carry + v;             // inclusive prefix P_j
                carry += __shfl(v, 63);          // segment total
            }
        }
        const float tot = carry;
        if (l == 0) Gg[idx0 * 64 + lcol] = -tot;             // e=0: 2*P(-1)-Tot
        #pragma unroll
        for (int s = 0; s < 4; ++s) {
            const int j = s * 64 + l;
            if (j <= r) Gg[(idx0 + 1 + j) * 64 + lcol] = 2.0f * Pseg[s] - tot;
        }
    }
}

// ---- K2: serial combine over chunks (thread = row)
__global__ __launch_bounds__(256)
void k2_combine(const int2* __restrict__ lohi, int* __restrict__ Eg, int NCH) {
    const int r = threadIdx.x;
    int c = -1;                                  // initial state
    #pragma unroll 4
    for (int i = 0; i < NCH; ++i) {
        Eg[i * 256 + r] = c;                     // entry state for chunk i
        const int2 lh = lohi[i * 256 + r];
        c = max(min(c, lh.y), lh.x);
    }
}

// ---- K3: per-chunk replay + evaluation
__global__ __launch_bounds__(64)
void k3_eval(const int* __restrict__ codes, const int* __restrict__ Eg,
             const float* __restrict__ Gg,
             const float* __restrict__ scale, const float* __restrict__ offset,
             float* __restrict__ out, int T) {
    __shared__ __align__(16) float Gl[GSZ];      // 132.6 KB
    __shared__ float cb[CL * 65];                // partials, conflict-free
    __shared__ int cds[CL];

    const int i = blockIdx.x;                    // chunk
    const int l = threadIdx.x;                   // lane

    // stage G: straight coalesced float4 copy (33152 floats = 8288 float4)
    const float4* __restrict__ Gf4 = (const float4*)Gg;
    float4* Gl4 = (float4*)Gl;
    for (int j = l; j < GSZ / 4; j += 64) Gl4[j] = Gf4[j];

    if (l < CL) cds[l] = codes[i * CL + l];

    const int rows[4] = { l, 64 + l, 191 - l, 255 - l };
    const int base[4] = { 1, 260, 326 + l, l + 3 };   // (idx0 + 1): addr=(base+c)*64+l
    int c0 = Eg[i * 256 + rows[0]];
    int c1 = Eg[i * 256 + rows[1]];
    int c2 = Eg[i * 256 + rows[2]];
    int c3 = Eg[i * 256 + rows[3]];
    __syncthreads();

    #pragma unroll 4
    for (int s = 0; s < CL; ++s) {
        const int cd = cds[s];
        const int k = cd & 0xFFFF, u = cd >> 16;
        c0 = max(min(c0, k), (rows[0] < u) ? rows[0] : -1);
        c1 = max(min(c1, k), (rows[1] < u) ? rows[1] : -1);
        c2 = max(min(c2, k), (rows[2] < u) ? rows[2] : -1);
        c3 = max(min(c3, k), (rows[3] < u) ? rows[3] : -1);
        const float p = Gl[(base[0] + c0) * 64 + l] + Gl[(base[1] + c1) * 64 + l]
                      + Gl[(base[2] + c2) * 64 + l] + Gl[(base[3] + c3) * 64 + l];
        cb[s * 65 + l] = p;
    }
    __syncthreads();

    if (l < CL) {
        const int t = i * CL + l;
        if (t < T) {
            float sum = 0.0f;
            #pragma unroll
            for (int j = 0; j < 64; ++j) sum += cb[l * 65 + j];
            out[t] = sum * (1.0f / 32896.0f) * scale[0] + offset[0];
        }
    }
}

extern "C" void kernel_launch(void* const* d_in, const int* in_sizes, int n_in,
                              void* d_out, int out_size, void* d_ws, size_t ws_size,
                              hipStream_t stream) {
    const float* h      = (const float*)d_in[0];
    const float* raw    = (const float*)d_in[1];
    const float* offset = (const float*)d_in[2];
    const float* scale  = (const float*)d_in[3];
    float* out = (float*)d_out;
    const int T = in_sizes[0];
    const int NCH = (T + CL - 1) / CL;

    // ws carve-up (all 16B-aligned)
    char* ws = (char*)d_ws;
    size_t o = 0;
    int* codes = (int*)(ws + o);  o += ((size_t)NCH * CL * 4 + 15) & ~15ull;
    int2* lohi = (int2*)(ws + o); o += (size_t)NCH * 256 * 8;
    int* Eg    = (int*)(ws + o);  o += (size_t)NCH * 256 * 4;
    float* Gg  = (float*)(ws + o);  // GSZ*4 = 132608 B

    k1_compose_gbuild<<<NCH + 256, 256, 0, stream>>>(h, raw, codes, lohi, Gg, T, NCH);
    k2_combine<<<1, 256, 0, stream>>>(lohi, Eg, NCH);
    k3_eval<<<NCH, 64, 0, stream>>>(codes, Eg, Gg, scale, offset, out, T);
}

// Round 5
// 81.365 us; speedup vs baseline: 8.3072x; 1.3355x over previous
//
#include <hip/hip_runtime.h>
#include <math.h>

// Preisach hysteresis, N=256, parallel-in-time (clamp-scan), 2 dispatches.
//
// Per row i the state is a staircase: +1 for j<=c_i, -1 for c_i<j<=i.
// Step update: c = max(min(c, k_t), r_t) with
//   up   (h>hp): k=256, r = (row < u_t ? row : -1),  u_t = #{i : i*d < h}
//   down (h<hp): k = max{j : j*d <= h},  r = -1
// Clamps compose: a chunk of steps == c -> max(min(c,HI),LO), with (LO,HI)
// obtained by running the chunk on seeds (-1, 256).
//   K1: per-chunk codes + per-row (LO,HI); G table build (global ws)
//   K3: 4 waves/block, chunk/wave: stage G to LDS (256-thread copy),
//       per-wave entry-state scan over lohi (replaces old serial K2 kernel),
//       32-step replay + per-step butterfly reduce -> out[t]. No atomics.
//
// G layout ("pair packing"): lane l owns rows {l, 255-l, 64+l, 191-l};
// concatenated column is exactly 518 floats for every lane. Stored
// e-interleaved: addr = idx*64 + l -> lane-private bank (2-way = free).
//   row l     : idx0 = 0        row 255-l : idx0 = l+2
//   row 64+l  : idx0 = 259      row 191-l : idx0 = 325+l
// G_r[e] = 2*P_r(e-1) - Tot_r,  P = prefix sums of softplus(raw), e in [0,r+1].

#define CL 32               // chunk length (time steps per chunk)
#define GSZ (518 * 64)      // packed G table, floats (132608 B)

__device__ __forceinline__ int make_code(const float* __restrict__ h, int t, int T) {
    const float delta = 1.0f / 255.0f;          // fl(1/255), matches jnp.linspace
    int code = 256;                              // no-op: k=256, u=0
    if (t < T) {
        const float hc = h[t];
        const float hp = (t == 0) ? 0.0f : h[t - 1];
        if (hc > hp) {
            // u-1 = max{ i : (float)i*delta < hc }   (yy >= h keeps state)
            int i2 = (int)(hc * 255.0f);
            if (i2 > 255) i2 = 255;
            while (i2 < 255 && (float)(i2 + 1) * delta < hc) ++i2;
            while (i2 >= 0 && (float)i2 * delta >= hc) --i2;
            code = ((i2 + 1) << 16) | 256;
        } else if (hc < hp) {
            // k = max{ j : (float)j*delta <= hc }    (xx <= h keeps state)
            int kk = (int)(hc * 255.0f);
            if (kk > 255) kk = 255;
            while (kk < 255 && (float)(kk + 1) * delta <= hc) ++kk;
            while (kk > 0 && (float)kk * delta > hc) --kk;
            code = kk;
        }
    }
    return code;
}

// ---- K1: blocks [0,NB3): codes + per-row clamp compose (1 chunk per wave)
//          blocks [NB3, NB3+64): G build (1 row per wave)
__global__ __launch_bounds__(256)
void k1_compose_gbuild(const float* __restrict__ h, const float* __restrict__ raw,
                       int* __restrict__ codes, int2* __restrict__ lohi,
                       float* __restrict__ Gg, int T, int NCH, int NB3) {
    const int b = blockIdx.x;
    const int tid = threadIdx.x;
    const int w = tid >> 6, l = tid & 63;
    if (b < NB3) {
        const int q = b * 4 + w;                 // chunk for this wave
        if (q >= NCH) return;
        int mycode = 256;
        if (l < CL) {
            mycode = make_code(h, q * CL + l, T);
            codes[q * CL + l] = mycode;
        }
        // compose chunk clamp for rows r = 64*j + l (shfl-broadcast the codes)
        int lo[4] = {-1, -1, -1, -1}, hi[4] = {256, 256, 256, 256};
        #pragma unroll
        for (int s = 0; s < CL; ++s) {
            const int cd = __shfl(mycode, s);
            const int k = cd & 0xFFFF, u = cd >> 16;
            #pragma unroll
            for (int j = 0; j < 4; ++j) {
                const int r = j * 64 + l;
                const int rr = (r < u) ? r : -1;
                lo[j] = max(min(lo[j], k), rr);
                hi[j] = max(min(hi[j], k), rr);
            }
        }
        #pragma unroll
        for (int j = 0; j < 4; ++j)
            lohi[q * 256 + j * 64 + l] = make_int2(lo[j], hi[j]);
    } else {
        // ---- G build: wave (b-NB3)*4 + w builds row r
        const int r = (b - NB3) * 4 + w;
        const int tri = r * (r + 1) / 2;
        int lcol, idx0;
        if (r < 64)       { lcol = r;       idx0 = 0; }
        else if (r < 128) { lcol = r - 64;  idx0 = 259; }
        else if (r < 192) { lcol = 191 - r; idx0 = 325 + lcol; }
        else              { lcol = 255 - r; idx0 = lcol + 2; }

        float Pseg[4];
        float carry = 0.0f;
        const int nseg = r / 64 + 1;
        #pragma unroll
        for (int s = 0; s < 4; ++s) {
            Pseg[s] = 0.0f;
            if (s < nseg) {
                const int j = s * 64 + l;
                float v = 0.0f;
                if (j <= r) {
                    const float x = raw[tri + j];
                    // jax.nn.softplus(x) = max(x,0) + log1p(exp(-|x|))
                    v = fmaxf(x, 0.0f) + log1pf(expf(-fabsf(x)));
                }
                #pragma unroll
                for (int off = 1; off < 64; off <<= 1) {
                    const float t2 = __shfl_up(v, off);
                    if (l >= off) v += t2;
                }
                Pseg[s] = carry + v;             // inclusive prefix P_j
                carry += __shfl(v, 63);          // segment total
            }
        }
        const float tot = carry;
        if (l == 0) Gg[idx0 * 64 + lcol] = -tot;             // e=0: 2*P(-1)-Tot
        #pragma unroll
        for (int s = 0; s < 4; ++s) {
            const int j = s * 64 + l;
            if (j <= r) Gg[(idx0 + 1 + j) * 64 + lcol] = 2.0f * Pseg[s] - tot;
        }
    }
}

// ---- K3: 4 waves/block, one chunk per wave; entry-state scan + replay + out
__global__ __launch_bounds__(256)
void k3_eval(const int* __restrict__ codes, const int2* __restrict__ lohi,
             const float* __restrict__ Gg,
             const float* __restrict__ scale, const float* __restrict__ offset,
             float* __restrict__ out, int T, int NCH) {
    __shared__ __align__(16) float Gl[GSZ];      // 132608 B
    __shared__ __align__(16) int cds[4 * CL];    // 512 B

    const int tid = threadIdx.x;
    const int w = tid >> 6, l = tid & 63;
    const int i = blockIdx.x;
    const int q = i * 4 + w;                     // chunk for this wave

    // stage G: coalesced float4 copy, all 4 waves participate (8288 vec4)
    {
        const float4* __restrict__ Gf4 = (const float4*)Gg;
        float4* Gl4 = (float4*)Gl;
        #pragma unroll 4
        for (int j = tid; j < GSZ / 4; j += 256) Gl4[j] = Gf4[j];
    }
    if (tid < 4 * CL) {
        const int gi = i * 4 * CL + tid;
        cds[tid] = (gi < NCH * CL) ? codes[gi] : 256;
    }
    __syncthreads();

    if (q < NCH) {
        const int rows[4] = { l, 64 + l, 191 - l, 255 - l };
        const int base[4] = { 1, 260, 326 + l, l + 3 };  // idx0+1: addr=(base+c)*64+l
        int c0 = -1, c1 = -1, c2 = -1, c3 = -1;

        // entry state: scan prior chunks' (LO,HI); loads coalesced & independent
        #pragma unroll 4
        for (int j = 0; j < q; ++j) {
            const int2 a = lohi[j * 256 + rows[0]];
            const int2 b2 = lohi[j * 256 + rows[1]];
            const int2 cc = lohi[j * 256 + rows[2]];
            const int2 d = lohi[j * 256 + rows[3]];
            c0 = max(min(c0, a.y), a.x);
            c1 = max(min(c1, b2.y), b2.x);
            c2 = max(min(c2, cc.y), cc.x);
            c3 = max(min(c3, d.y), d.x);
        }

        // replay: 4 rows/lane, per-step butterfly reduce; lane s keeps step s
        float myout = 0.0f;
        #pragma unroll 4
        for (int s = 0; s < CL; ++s) {
            const int cd = cds[w * CL + s];      // wave-uniform -> broadcast
            const int k = cd & 0xFFFF, u = cd >> 16;
            c0 = max(min(c0, k), (rows[0] < u) ? rows[0] : -1);
            c1 = max(min(c1, k), (rows[1] < u) ? rows[1] : -1);
            c2 = max(min(c2, k), (rows[2] < u) ? rows[2] : -1);
            c3 = max(min(c3, k), (rows[3] < u) ? rows[3] : -1);
            float p = Gl[(base[0] + c0) * 64 + l] + Gl[(base[1] + c1) * 64 + l]
                    + Gl[(base[2] + c2) * 64 + l] + Gl[(base[3] + c3) * 64 + l];
            #pragma unroll
            for (int off = 32; off; off >>= 1) p += __shfl_xor(p, off);
            if (l == s) myout = p;
        }
        const int t = q * CL + l;
        if (l < CL && t < T)
            out[t] = myout * (1.0f / 32896.0f) * scale[0] + offset[0];
    }
}

extern "C" void kernel_launch(void* const* d_in, const int* in_sizes, int n_in,
                              void* d_out, int out_size, void* d_ws, size_t ws_size,
                              hipStream_t stream) {
    const float* h      = (const float*)d_in[0];
    const float* raw    = (const float*)d_in[1];
    const float* offset = (const float*)d_in[2];
    const float* scale  = (const float*)d_in[3];
    float* out = (float*)d_out;
    const int T = in_sizes[0];
    const int NCH = (T + CL - 1) / CL;           // chunks
    const int NB3 = (NCH + 3) / 4;               // 4 chunks (waves) per block

    // ws carve-up (16B-aligned)
    char* ws = (char*)d_ws;
    size_t o = 0;
    int* codes = (int*)(ws + o);  o += ((size_t)NCH * CL * 4 + 15) & ~15ull;
    int2* lohi = (int2*)(ws + o); o += (size_t)NCH * 256 * 8;
    float* Gg  = (float*)(ws + o);               // GSZ*4 = 132608 B

    k1_compose_gbuild<<<NB3 + 64, 256, 0, stream>>>(h, raw, codes, lohi, Gg, T, NCH, NB3);
    k3_eval<<<NB3, 256, 0, stream>>>(codes, lohi, Gg, scale, offset, out, T, NCH);
}